// Round 1
// baseline (920.343 us; speedup 1.0000x reference)
//
#include <hip/hip_runtime.h>
#include <hip/hip_bf16.h>
#include <math.h>

// Problem constants
#define B_    8
#define C_    64
#define H_    64
#define W_    64
#define NUM_EMBED 8192
#define DIMS  64
#define N_TOK (B_ * H_ * W_)           // 32768
#define N_ELEM (B_ * C_ * H_ * W_)     // 2097152

// ---------------------------------------------------------------------------
// K1: normalize embedding rows -> en  (en[k] = emb[k] / ||emb[k]||)
// 4 rows per 256-thread block (one wave per row)
// ---------------------------------------------------------------------------
__global__ void norm_emb_kernel(const float* __restrict__ emb, float* __restrict__ en) {
    int wave = threadIdx.x >> 6;
    int lane = threadIdx.x & 63;
    int row  = blockIdx.x * 4 + wave;
    float v = emb[row * DIMS + lane];
    float s = v * v;
    #pragma unroll
    for (int off = 1; off < 64; off <<= 1) s += __shfl_xor(s, off, 64);
    en[row * DIMS + lane] = v / sqrtf(s);
}

// ---------------------------------------------------------------------------
// K2: fused similarity matmul + argmax.
// Block: 512 threads (8 waves), handles 128 tokens (2 rows of w).
// Each lane holds 2 tokens' 64 channels in VGPRs.
// Codebook staged in LDS tiles of 128 codes (32 KB); wave w takes 16 codes/tile.
// ---------------------------------------------------------------------------
#define TILE 128
#define WAVES2 8
#define CPWT (TILE / WAVES2)   // 16 codes per wave per tile

__global__ __launch_bounds__(512, 2)
void argmax_kernel(const float* __restrict__ z, const float* __restrict__ en,
                   int* __restrict__ idx, float* __restrict__ idxmap) {
    __shared__ float lds_en[TILE * DIMS];     // 32 KB
    __shared__ float smax[WAVES2][128];       // 4 KB
    __shared__ int   sidx[WAVES2][128];       // 4 KB

    const int tid  = threadIdx.x;
    const int lane = tid & 63;
    const int wave = tid >> 6;
    const int bt   = blockIdx.x;              // 0..255
    const int b    = bt >> 5;
    const int hh   = (bt & 31) * 2;           // h of first token row

    // Load 2 tokens (h = hh, hh+1), 64 channels each, into registers.
    const float* zb = z + b * (C_ * H_ * W_) + hh * W_ + lane;
    float z0[DIMS], z1[DIMS];
    #pragma unroll
    for (int c = 0; c < DIMS; ++c) {
        z0[c] = zb[c * (H_ * W_)];
        z1[c] = zb[c * (H_ * W_) + W_];
    }

    float best0 = -1e30f, best1 = -1e30f;
    int bi0 = 0, bi1 = 0;

    for (int t0 = 0; t0 < NUM_EMBED; t0 += TILE) {
        __syncthreads();   // previous tile fully consumed
        // stage TILE*DIMS = 8192 floats with 512 threads -> 4 float4 each
        const float4* src = (const float4*)(en + t0 * DIMS);
        float4* dst = (float4*)lds_en;
        #pragma unroll
        for (int i = 0; i < 4; ++i) dst[tid + i * 512] = src[tid + i * 512];
        __syncthreads();

        #pragma unroll 2
        for (int j = 0; j < CPWT; ++j) {
            const int local = wave * CPWT + j;
            const float4* e4 = (const float4*)(lds_en + local * DIMS);
            float a0 = 0.f, a1 = 0.f, a2 = 0.f, a3 = 0.f;
            float c0 = 0.f, c1 = 0.f, c2 = 0.f, c3 = 0.f;
            #pragma unroll
            for (int q = 0; q < DIMS / 4; ++q) {
                float4 e = e4[q];                // uniform addr: LDS broadcast
                a0 += z0[q * 4 + 0] * e.x;  a1 += z0[q * 4 + 1] * e.y;
                a2 += z0[q * 4 + 2] * e.z;  a3 += z0[q * 4 + 3] * e.w;
                c0 += z1[q * 4 + 0] * e.x;  c1 += z1[q * 4 + 1] * e.y;
                c2 += z1[q * 4 + 2] * e.z;  c3 += z1[q * 4 + 3] * e.w;
            }
            float d0 = (a0 + a1) + (a2 + a3);
            float d1 = (c0 + c1) + (c2 + c3);
            const int code = t0 + local;
            if (d0 > best0) { best0 = d0; bi0 = code; }   // strict >: earliest wins
            if (d1 > best1) { best1 = d1; bi1 = code; }
        }
    }

    smax[wave][lane]      = best0;  sidx[wave][lane]      = bi0;
    smax[wave][lane + 64] = best1;  sidx[wave][lane + 64] = bi1;
    __syncthreads();

    if (tid < 128) {
        float bm = smax[0][tid]; int bix = sidx[0][tid];
        #pragma unroll
        for (int w = 1; w < WAVES2; ++w) {
            float m = smax[w][tid]; int ix = sidx[w][tid];
            if (m > bm || (m == bm && ix < bix)) { bm = m; bix = ix; }
        }
        const int t = bt * 128 + tid;   // global token id (b,h,w linear)
        idx[t] = bix;
        idxmap[t] = (float)bix;
    }
}

// ---------------------------------------------------------------------------
// K3: gather z_q, write out = zv + (q - zv) (matches reference rounding),
// per-block SSE partial, histogram.
// 512 blocks x 256 threads; block = one (b,h) row of 64 tokens; wave covers
// 16 channels.
// ---------------------------------------------------------------------------
__global__ void gather_loss_kernel(const float* __restrict__ z,
                                   const float* __restrict__ emb,
                                   const int* __restrict__ idx,
                                   float* __restrict__ out,
                                   float* __restrict__ partial,
                                   int* __restrict__ hist) {
    __shared__ float red[256];
    const int tid  = threadIdx.x;
    const int lane = tid & 63;   // w
    const int wave = tid >> 6;
    const int bt   = blockIdx.x; // 0..511
    const int b    = bt >> 6;
    const int h    = bt & 63;

    const int t  = bt * 64 + lane;
    const int id = idx[t];
    const long base = (long)b * (C_ * H_ * W_) + h * W_ + lane;

    float sse = 0.f;
    #pragma unroll
    for (int cc = 0; cc < 16; ++cc) {
        const int c = wave * 16 + cc;
        const float q  = emb[id * DIMS + c];
        const float zv = z[base + (long)c * (H_ * W_)];
        out[base + (long)c * (H_ * W_)] = zv + (q - zv);  // exact ref expression
        const float d = q - zv;
        sse += d * d;
    }

    red[tid] = sse;
    __syncthreads();
    for (int s = 128; s > 0; s >>= 1) {
        if (tid < s) red[tid] += red[tid + s];
        __syncthreads();
    }
    if (tid == 0) partial[bt] = red[0];
    if (wave == 0) atomicAdd(&hist[id], 1);
    if (tid == 0 && bt == 0) { /* nothing */ }
}

// ---------------------------------------------------------------------------
// K4: finalize loss + perplexity. One block of 256 threads.
// out_scal[0] = loss, out_scal[1] = perplexity
// ---------------------------------------------------------------------------
__global__ void finalize_kernel(const float* __restrict__ partial,
                                const int* __restrict__ hist,
                                float* __restrict__ out_scal) {
    __shared__ double red[256];
    const int tid = threadIdx.x;

    double s = 0.0;
    for (int i = tid; i < 512; i += 256) s += (double)partial[i];
    red[tid] = s;
    __syncthreads();
    for (int st = 128; st > 0; st >>= 1) {
        if (tid < st) red[tid] += red[tid + st];
        __syncthreads();
    }
    const double sse = red[0];
    __syncthreads();

    double e = 0.0;
    for (int k = tid; k < NUM_EMBED; k += 256) {
        float p = (float)hist[k] / (float)N_TOK;
        e += (double)(p * logf(p + 1e-10f));
    }
    red[tid] = e;
    __syncthreads();
    for (int st = 128; st > 0; st >>= 1) {
        if (tid < st) red[tid] += red[tid + st];
        __syncthreads();
    }
    if (tid == 0) {
        out_scal[0] = (float)(1.25 * sse / (double)N_ELEM);
        out_scal[1] = expf(-(float)red[0]);
    }
}

// ---------------------------------------------------------------------------
extern "C" void kernel_launch(void* const* d_in, const int* in_sizes, int n_in,
                              void* d_out, int out_size, void* d_ws, size_t ws_size,
                              hipStream_t stream) {
    const float* z   = (const float*)d_in[0];
    const float* emb = (const float*)d_in[1];
    float* o = (float*)d_out;

    char* ws = (char*)d_ws;
    float* en      = (float*)ws;                                   // 2 MB
    int*   idx     = (int*)(ws + 2097152);                         // 128 KB
    int*   hist    = (int*)(ws + 2097152 + 131072);                // 32 KB
    float* partial = (float*)(ws + 2097152 + 131072 + 32768);      // 2 KB

    float* out_q      = o;                  // 2097152 floats
    float* out_scal   = o + N_ELEM;         // loss, perplexity
    float* out_idxmap = o + N_ELEM + 2;     // 32768 floats

    hipMemsetAsync(hist, 0, NUM_EMBED * sizeof(int), stream);
    norm_emb_kernel<<<NUM_EMBED / 4, 256, 0, stream>>>(emb, en);
    argmax_kernel<<<N_TOK / 128, 512, 0, stream>>>(z, en, idx, out_idxmap);
    gather_loss_kernel<<<N_TOK / 64, 256, 0, stream>>>(z, emb, idx, out_q, partial, hist);
    finalize_kernel<<<1, 256, 0, stream>>>(partial, hist, out_scal);
}

// Round 2
// 216.800 us; speedup vs baseline: 4.2451x; 4.2451x over previous
//
#include <hip/hip_runtime.h>
#include <hip/hip_bf16.h>
#include <math.h>

// Problem constants
#define B_    8
#define C_    64
#define H_    64
#define W_    64
#define NUM_EMBED 8192
#define DIMS  64
#define N_TOK (B_ * H_ * W_)           // 32768
#define N_ELEM (B_ * C_ * H_ * W_)     // 2097152

typedef short v8s __attribute__((ext_vector_type(8)));   // 8 bf16 = 4 VGPR
typedef float v4f __attribute__((ext_vector_type(4)));   // MFMA acc

#define MARGIN 0.011f   // rigorous bf16 bound 2*2^-8=0.0078, +40% headroom

// ---- helpers ---------------------------------------------------------------
__device__ __forceinline__ short bf16_rne(float x) {
    unsigned u = __float_as_uint(x);
    unsigned r = (u + 0x7FFFu + ((u >> 16) & 1u)) >> 16;
    return (short)r;
}
// monotone float->u32 (order-preserving, incl. negatives)
__device__ __forceinline__ unsigned mono(float f) {
    int b = __float_as_int(f);
    return (unsigned)(b ^ ((b >> 31) | 0x80000000));
}
__device__ __forceinline__ float demono(unsigned u) {
    int b = (u >> 31) ? (int)(u ^ 0x80000000u) : (int)~u;
    return __int_as_float(b);
}
__device__ __forceinline__ unsigned long long pack_win(float d, int code) {
    return ((unsigned long long)mono(d) << 32) | (unsigned)(0xFFFFFFFFu - (unsigned)code);
}

// ---------------------------------------------------------------------------
// P1: inverse row norms of embedding. 4 rows/block, one wave per row.
// ---------------------------------------------------------------------------
__global__ void invnorm_kernel(const float* __restrict__ emb, float* __restrict__ invn) {
    int wave = threadIdx.x >> 6;
    int lane = threadIdx.x & 63;
    int row  = blockIdx.x * 4 + wave;
    float v = emb[row * DIMS + lane];
    float s = v * v;
    #pragma unroll
    for (int off = 1; off < 64; off <<= 1) s += __shfl_xor(s, off, 64);
    if (lane == 0) invn[row] = 1.0f / sqrtf(s);
}

// ---------------------------------------------------------------------------
// P2: build B fragments: en_frag[(ct*2+st)*64 + lane] = 8 bf16 of
//     en[code = ct*16 + (lane&15)][k = st*32 + (lane>>4)*8 + j]
// ---------------------------------------------------------------------------
__global__ void en_frag_kernel(const float* __restrict__ emb, const float* __restrict__ invn,
                               v8s* __restrict__ ef) {
    int ch = blockIdx.x * 256 + threadIdx.x;      // 0..65535
    int l  = ch & 63;
    int st = (ch >> 6) & 1;
    int ct = ch >> 7;
    int code = ct * 16 + (l & 15);
    int kb   = st * 32 + ((l >> 4) & 3) * 8;
    float rn = invn[code];
    v8s o;
    #pragma unroll
    for (int j = 0; j < 8; ++j) o[j] = bf16_rne(emb[code * DIMS + kb + j] * rn);
    ef[ch] = o;
}

// ---------------------------------------------------------------------------
// P3: z -> z_tok (fp32 token-major, for exact rescore)  +  A fragments
//     (normalized bf16). Block = one (b,h) row = 64 tokens = 4 M-tiles.
// ---------------------------------------------------------------------------
__global__ __launch_bounds__(256)
void z_prep_kernel(const float* __restrict__ z, float* __restrict__ z_tok,
                   v8s* __restrict__ af) {
    __shared__ float zs[64][65];   // [c][token_local], +1 pad
    __shared__ float part[4][64];
    __shared__ float rn[64];
    const int tid = threadIdx.x;
    const int w   = tid & 63;
    const int cg  = tid >> 6;
    const int bh  = blockIdx.x;            // 0..511
    const int b   = bh >> 6, h = bh & 63;

    const float* zb = z + (size_t)b * (C_ * H_ * W_) + h * W_;
    float ss = 0.f;
    #pragma unroll
    for (int cc = 0; cc < 16; ++cc) {
        int c = cg * 16 + cc;
        float v = zb[c * (H_ * W_) + w];
        zs[c][w] = v;
        ss += v * v;
    }
    part[cg][w] = ss;
    __syncthreads();
    if (tid < 64) {
        float s = part[0][tid] + part[1][tid] + part[2][tid] + part[3][tid];
        rn[tid] = 1.0f / sqrtf(s);
    }
    __syncthreads();

    // z_tok[t][c], coalesced in c
    {
        int c  = tid & 63;
        int tg = tid >> 6;
        #pragma unroll
        for (int i = 0; i < 16; ++i) {
            int tloc = tg * 16 + i;
            z_tok[(size_t)(bh * 64 + tloc) * DIMS + c] = zs[c][tloc];
        }
    }
    // A fragments: 512 chunks (4 mtiles x 2 ksteps x 64 lanes), 2 per thread
    #pragma unroll
    for (int ii = 0; ii < 2; ++ii) {
        int ch  = tid + ii * 256;
        int mtl = ch >> 7;
        int st  = (ch >> 6) & 1;
        int l   = ch & 63;
        int tloc = mtl * 16 + (l & 15);
        int kb   = st * 32 + ((l >> 4) & 3) * 8;
        float rr = rn[tloc];
        v8s o;
        #pragma unroll
        for (int j = 0; j < 8; ++j) o[j] = bf16_rne(zs[kb + j][tloc] * rr);
        af[(size_t)((bh * 4 + mtl) * 2 + st) * 64 + l] = o;
    }
}

// ---------------------------------------------------------------------------
// Pass 1: bf16 MFMA GEMM, per-token max of bf16 scores -> atomicMax(mono u32).
// Block: 512 thr (8 waves). Wave owns RT=8 M-tiles (128 tokens), block covers
// 64 M-tiles (1024 tokens). Code split 8-way: block does 1024 codes = 64
// 16-code tiles, staged in LDS in chunks of 8 tiles (16 KB).
// Grid = 32 M-groups x 8 splits = 256 blocks.
// ---------------------------------------------------------------------------
#define RT 8
#define CHUNK_TILES 8
#define TILES_PER_BLOCK 64
#define CHUNKS (TILES_PER_BLOCK / CHUNK_TILES)

__global__ __launch_bounds__(512, 2)
void pass1_kernel(const v8s* __restrict__ af, const v8s* __restrict__ ef,
                  unsigned* __restrict__ tokmax) {
    __shared__ v8s lds[CHUNK_TILES * 2 * 64];   // 16 KB
    const int tid  = threadIdx.x;
    const int lane = tid & 63;
    const int wave = tid >> 6;
    const int mgrp  = blockIdx.x >> 3;
    const int split = blockIdx.x & 7;
    const int tile0 = split * TILES_PER_BLOCK;

    const int mtb = mgrp * 64 + wave * RT;
    v8s a[RT][2];
    #pragma unroll
    for (int r = 0; r < RT; ++r)
        #pragma unroll
        for (int s = 0; s < 2; ++s)
            a[r][s] = af[(size_t)((mtb + r) * 2 + s) * 64 + lane];

    v4f mx[RT];
    #pragma unroll
    for (int r = 0; r < RT; ++r) mx[r] = (v4f){-1e30f, -1e30f, -1e30f, -1e30f};

    const float4* gsrc = (const float4*)(ef + (size_t)tile0 * 2 * 64);
    float4* lf = (float4*)lds;
    float4 pre0 = gsrc[tid], pre1 = gsrc[tid + 512];

    for (int c = 0; c < CHUNKS; ++c) {
        __syncthreads();
        lf[tid] = pre0; lf[tid + 512] = pre1;
        if (c + 1 < CHUNKS) {
            const float4* nx = gsrc + (size_t)(c + 1) * 1024;
            pre0 = nx[tid]; pre1 = nx[tid + 512];
        }
        __syncthreads();
        #pragma unroll
        for (int j = 0; j < CHUNK_TILES; ++j) {
            v8s b0 = lds[(j * 2 + 0) * 64 + lane];
            v8s b1 = lds[(j * 2 + 1) * 64 + lane];
            #pragma unroll
            for (int r = 0; r < RT; ++r) {
                v4f t = (v4f){0.f, 0.f, 0.f, 0.f};
                t = __builtin_amdgcn_mfma_f32_16x16x32_bf16(a[r][0], b0, t, 0, 0, 0);
                t = __builtin_amdgcn_mfma_f32_16x16x32_bf16(a[r][1], b1, t, 0, 0, 0);
                mx[r][0] = fmaxf(mx[r][0], t[0]);
                mx[r][1] = fmaxf(mx[r][1], t[1]);
                mx[r][2] = fmaxf(mx[r][2], t[2]);
                mx[r][3] = fmaxf(mx[r][3], t[3]);
            }
        }
    }
    // reduce over the 16 code-columns (lanes sharing quad)
    #pragma unroll
    for (int r = 0; r < RT; ++r)
        #pragma unroll
        for (int i = 0; i < 4; ++i) {
            float v = mx[r][i];
            v = fmaxf(v, __shfl_xor(v, 1, 64));
            v = fmaxf(v, __shfl_xor(v, 2, 64));
            v = fmaxf(v, __shfl_xor(v, 4, 64));
            v = fmaxf(v, __shfl_xor(v, 8, 64));
            mx[r][i] = v;
        }
    if ((lane & 15) == 0) {
        int q = lane >> 4;
        #pragma unroll
        for (int r = 0; r < RT; ++r)
            #pragma unroll
            for (int i = 0; i < 4; ++i) {
                int tok = (mtb + r) * 16 + q * 4 + i;
                atomicMax(&tokmax[tok], mono(mx[r][i]));
            }
    }
}

// ---------------------------------------------------------------------------
// Pass 2: same GEMM; codes with s_bf >= tokmax - MARGIN get exact fp32
// rescore (wave-cooperative dot on z_tok, emb, invn) -> packed u64 atomicMax
// (max value, tie -> smallest code index).
// ---------------------------------------------------------------------------
__global__ __launch_bounds__(512, 2)
void pass2_kernel(const v8s* __restrict__ af, const v8s* __restrict__ ef,
                  const unsigned* __restrict__ tokmax,
                  const float* __restrict__ z_tok, const float* __restrict__ emb,
                  const float* __restrict__ invn,
                  unsigned long long* __restrict__ winner) {
    __shared__ v8s lds[CHUNK_TILES * 2 * 64];
    const int tid  = threadIdx.x;
    const int lane = tid & 63;
    const int wave = tid >> 6;
    const int mgrp  = blockIdx.x >> 3;
    const int split = blockIdx.x & 7;
    const int tile0 = split * TILES_PER_BLOCK;

    const int mtb = mgrp * 64 + wave * RT;
    v8s a[RT][2];
    #pragma unroll
    for (int r = 0; r < RT; ++r)
        #pragma unroll
        for (int s = 0; s < 2; ++s)
            a[r][s] = af[(size_t)((mtb + r) * 2 + s) * 64 + lane];

    // per-lane thresholds for its 32 (row, reg) tokens
    float thr[RT][4];
    {
        int q = lane >> 4;
        #pragma unroll
        for (int r = 0; r < RT; ++r)
            #pragma unroll
            for (int i = 0; i < 4; ++i)
                thr[r][i] = demono(tokmax[(mtb + r) * 16 + q * 4 + i]) - MARGIN;
    }

    const float4* gsrc = (const float4*)(ef + (size_t)tile0 * 2 * 64);
    float4* lf = (float4*)lds;
    float4 pre0 = gsrc[tid], pre1 = gsrc[tid + 512];

    for (int c = 0; c < CHUNKS; ++c) {
        __syncthreads();
        lf[tid] = pre0; lf[tid + 512] = pre1;
        if (c + 1 < CHUNKS) {
            const float4* nx = gsrc + (size_t)(c + 1) * 1024;
            pre0 = nx[tid]; pre1 = nx[tid + 512];
        }
        __syncthreads();
        for (int j = 0; j < CHUNK_TILES; ++j) {
            v8s b0 = lds[(j * 2 + 0) * 64 + lane];
            v8s b1 = lds[(j * 2 + 1) * 64 + lane];
            v4f acc[RT];
            #pragma unroll
            for (int r = 0; r < RT; ++r) {
                v4f t = (v4f){0.f, 0.f, 0.f, 0.f};
                t = __builtin_amdgcn_mfma_f32_16x16x32_bf16(a[r][0], b0, t, 0, 0, 0);
                t = __builtin_amdgcn_mfma_f32_16x16x32_bf16(a[r][1], b1, t, 0, 0, 0);
                acc[r] = t;
            }
            bool cand = false;
            #pragma unroll
            for (int r = 0; r < RT; ++r)
                #pragma unroll
                for (int i = 0; i < 4; ++i)
                    cand |= (acc[r][i] >= thr[r][i]);
            if (__ballot(cand)) {                     // wave-uniform, rare (~28%)
                const int ctile = tile0 + c * CHUNK_TILES + j;
                #pragma unroll
                for (int r = 0; r < RT; ++r)
                    #pragma unroll
                    for (int i = 0; i < 4; ++i) {
                        unsigned long long m = __ballot(acc[r][i] >= thr[r][i]);
                        while (m) {
                            int sl = __ffsll(m) - 1;
                            m &= m - 1;
                            int tok  = (mtb + r) * 16 + ((sl >> 4) & 3) * 4 + i;
                            int code = ctile * 16 + (sl & 15);
                            // exact fp32 rescore, whole wave cooperates
                            float p = z_tok[(size_t)tok * DIMS + lane] *
                                      emb[(size_t)code * DIMS + lane];
                            #pragma unroll
                            for (int o = 32; o; o >>= 1) p += __shfl_xor(p, o, 64);
                            float d = p * invn[code];
                            if (lane == 0) atomicMax(&winner[tok], pack_win(d, code));
                        }
                    }
            }
        }
    }
}

// ---------------------------------------------------------------------------
// Finalize indices: unpack winner -> idx (int) + idxmap (float out)
// ---------------------------------------------------------------------------
__global__ void fin_idx_kernel(const unsigned long long* __restrict__ winner,
                               int* __restrict__ idx, float* __restrict__ idxmap) {
    int t = blockIdx.x * 256 + threadIdx.x;
    unsigned code = 0xFFFFFFFFu - (unsigned)(winner[t] & 0xFFFFFFFFull);
    idx[t] = (int)code;
    idxmap[t] = (float)code;
}

// ---------------------------------------------------------------------------
// K3: gather z_q, out = zv + (q - zv), SSE partial, histogram. (unchanged)
// ---------------------------------------------------------------------------
__global__ void gather_loss_kernel(const float* __restrict__ z,
                                   const float* __restrict__ emb,
                                   const int* __restrict__ idx,
                                   float* __restrict__ out,
                                   float* __restrict__ partial,
                                   int* __restrict__ hist) {
    __shared__ float red[256];
    const int tid  = threadIdx.x;
    const int lane = tid & 63;   // w
    const int wave = tid >> 6;
    const int bt   = blockIdx.x; // 0..511
    const int b    = bt >> 6;
    const int h    = bt & 63;

    const int t  = bt * 64 + lane;
    const int id = idx[t];
    const long base = (long)b * (C_ * H_ * W_) + h * W_ + lane;

    float sse = 0.f;
    #pragma unroll
    for (int cc = 0; cc < 16; ++cc) {
        const int c = wave * 16 + cc;
        const float q  = emb[id * DIMS + c];
        const float zv = z[base + (long)c * (H_ * W_)];
        out[base + (long)c * (H_ * W_)] = zv + (q - zv);  // exact ref expression
        const float d = q - zv;
        sse += d * d;
    }

    red[tid] = sse;
    __syncthreads();
    for (int s = 128; s > 0; s >>= 1) {
        if (tid < s) red[tid] += red[tid + s];
        __syncthreads();
    }
    if (tid == 0) partial[bt] = red[0];
    if (wave == 0) atomicAdd(&hist[id], 1);
}

// ---------------------------------------------------------------------------
// K4: finalize loss + perplexity. (unchanged)
// ---------------------------------------------------------------------------
__global__ void finalize_kernel(const float* __restrict__ partial,
                                const int* __restrict__ hist,
                                float* __restrict__ out_scal) {
    __shared__ double red[256];
    const int tid = threadIdx.x;

    double s = 0.0;
    for (int i = tid; i < 512; i += 256) s += (double)partial[i];
    red[tid] = s;
    __syncthreads();
    for (int st = 128; st > 0; st >>= 1) {
        if (tid < st) red[tid] += red[tid + st];
        __syncthreads();
    }
    const double sse = red[0];
    __syncthreads();

    double e = 0.0;
    for (int k = tid; k < NUM_EMBED; k += 256) {
        float p = (float)hist[k] / (float)N_TOK;
        e += (double)(p * logf(p + 1e-10f));
    }
    red[tid] = e;
    __syncthreads();
    for (int st = 128; st > 0; st >>= 1) {
        if (tid < st) red[tid] += red[tid + st];
        __syncthreads();
    }
    if (tid == 0) {
        out_scal[0] = (float)(1.25 * sse / (double)N_ELEM);
        out_scal[1] = expf(-(float)red[0]);
    }
}

// ---------------------------------------------------------------------------
extern "C" void kernel_launch(void* const* d_in, const int* in_sizes, int n_in,
                              void* d_out, int out_size, void* d_ws, size_t ws_size,
                              hipStream_t stream) {
    const float* z   = (const float*)d_in[0];
    const float* emb = (const float*)d_in[1];
    float* o = (float*)d_out;

    // workspace layout (5.57 MB total)
    char* ws = (char*)d_ws;
    v8s*  af      = (v8s*)ws;                                      // 4 MB
    v8s*  ef      = (v8s*)(ws + 4194304);                          // 1 MB
    unsigned long long* winner = (unsigned long long*)(ws + 5242880); // 256 KB
    unsigned* tokmax = (unsigned*)(ws + 5505024);                  // 128 KB
    int*   idx     = (int*)(ws + 5636096);                         // 128 KB
    float* invn    = (float*)(ws + 5767168);                       // 32 KB
    int*   hist    = (int*)(ws + 5799936);                         // 32 KB
    float* partial = (float*)(ws + 5832704);                       // 2 KB

    float* out_q      = o;                  // 2097152 floats
    float* out_scal   = o + N_ELEM;         // loss, perplexity
    float* out_idxmap = o + N_ELEM + 2;     // 32768 floats
    float* z_tok      = o;                  // reuse out_q region as fp32 token-major
                                            // scratch; overwritten by gather later

    hipMemsetAsync(tokmax, 0, N_TOK * sizeof(unsigned), stream);
    hipMemsetAsync(winner, 0, N_TOK * sizeof(unsigned long long), stream);
    hipMemsetAsync(hist,   0, NUM_EMBED * sizeof(int), stream);

    invnorm_kernel<<<NUM_EMBED / 4, 256, 0, stream>>>(emb, invn);
    en_frag_kernel<<<256, 256, 0, stream>>>(emb, invn, ef);
    z_prep_kernel<<<512, 256, 0, stream>>>(z, z_tok, af);
    pass1_kernel<<<256, 512, 0, stream>>>(af, ef, tokmax);
    pass2_kernel<<<256, 512, 0, stream>>>(af, ef, tokmax, z_tok, emb, invn, winner);
    fin_idx_kernel<<<N_TOK / 256, 256, 0, stream>>>(winner, idx, out_idxmap);
    gather_loss_kernel<<<N_TOK / 64, 256, 0, stream>>>(z, emb, idx, out_q, partial, hist);
    finalize_kernel<<<1, 256, 0, stream>>>(partial, hist, out_scal);
}

// Round 3
// 198.842 us; speedup vs baseline: 4.6285x; 1.0903x over previous
//
#include <hip/hip_runtime.h>
#include <hip/hip_bf16.h>
#include <math.h>

// Problem constants
#define B_    8
#define C_    64
#define H_    64
#define W_    64
#define NUM_EMBED 8192
#define DIMS  64
#define N_TOK (B_ * H_ * W_)           // 32768
#define N_ELEM (B_ * C_ * H_ * W_)     // 2097152

typedef short v8s __attribute__((ext_vector_type(8)));   // 8 bf16 = 4 VGPR
typedef float v4f __attribute__((ext_vector_type(4)));   // MFMA acc

#define MARGIN 0.011f   // rigorous bf16 bound 2*2^-8=0.0078, +40% headroom

// ---- helpers ---------------------------------------------------------------
__device__ __forceinline__ short bf16_rne(float x) {
    unsigned u = __float_as_uint(x);
    unsigned r = (u + 0x7FFFu + ((u >> 16) & 1u)) >> 16;
    return (short)r;
}
// monotone float->u32 (order-preserving, incl. negatives)
__device__ __forceinline__ unsigned mono(float f) {
    int b = __float_as_int(f);
    return (unsigned)(b ^ ((b >> 31) | 0x80000000));
}
__device__ __forceinline__ float demono(unsigned u) {
    int b = (u >> 31) ? (int)(u ^ 0x80000000u) : (int)~u;
    return __int_as_float(b);
}
__device__ __forceinline__ unsigned long long pack_win(float d, int code) {
    return ((unsigned long long)mono(d) << 32) | (unsigned)(0xFFFFFFFFu - (unsigned)code);
}

// ---------------------------------------------------------------------------
// P1: inverse row norms of embedding. 4 rows/block, one wave per row.
// ---------------------------------------------------------------------------
__global__ void invnorm_kernel(const float* __restrict__ emb, float* __restrict__ invn) {
    int wave = threadIdx.x >> 6;
    int lane = threadIdx.x & 63;
    int row  = blockIdx.x * 4 + wave;
    float v = emb[row * DIMS + lane];
    float s = v * v;
    #pragma unroll
    for (int off = 1; off < 64; off <<= 1) s += __shfl_xor(s, off, 64);
    if (lane == 0) invn[row] = 1.0f / sqrtf(s);
}

// ---------------------------------------------------------------------------
// P2: build B fragments: en_frag[(ct*2+st)*64 + lane] = 8 bf16 of
//     en[code = ct*16 + (lane&15)][k = st*32 + (lane>>4)*8 + j]
// ---------------------------------------------------------------------------
__global__ void en_frag_kernel(const float* __restrict__ emb, const float* __restrict__ invn,
                               v8s* __restrict__ ef) {
    int ch = blockIdx.x * 256 + threadIdx.x;      // 0..65535
    int l  = ch & 63;
    int st = (ch >> 6) & 1;
    int ct = ch >> 7;
    int code = ct * 16 + (l & 15);
    int kb   = st * 32 + ((l >> 4) & 3) * 8;
    float rn = invn[code];
    v8s o;
    #pragma unroll
    for (int j = 0; j < 8; ++j) o[j] = bf16_rne(emb[code * DIMS + kb + j] * rn);
    ef[ch] = o;
}

// ---------------------------------------------------------------------------
// P3: z -> z_tok (fp32 token-major, for exact rescore)  +  A fragments
//     (normalized bf16). Block = one (b,h) row = 64 tokens = 4 M-tiles.
// ---------------------------------------------------------------------------
__global__ __launch_bounds__(256)
void z_prep_kernel(const float* __restrict__ z, float* __restrict__ z_tok,
                   v8s* __restrict__ af) {
    __shared__ float zs[64][65];   // [c][token_local], +1 pad
    __shared__ float part[4][64];
    __shared__ float rn[64];
    const int tid = threadIdx.x;
    const int w   = tid & 63;
    const int cg  = tid >> 6;
    const int bh  = blockIdx.x;            // 0..511
    const int b   = bh >> 6, h = bh & 63;

    const float* zb = z + (size_t)b * (C_ * H_ * W_) + h * W_;
    float ss = 0.f;
    #pragma unroll
    for (int cc = 0; cc < 16; ++cc) {
        int c = cg * 16 + cc;
        float v = zb[c * (H_ * W_) + w];
        zs[c][w] = v;
        ss += v * v;
    }
    part[cg][w] = ss;
    __syncthreads();
    if (tid < 64) {
        float s = part[0][tid] + part[1][tid] + part[2][tid] + part[3][tid];
        rn[tid] = 1.0f / sqrtf(s);
    }
    __syncthreads();

    // z_tok[t][c], coalesced in c
    {
        int c  = tid & 63;
        int tg = tid >> 6;
        #pragma unroll
        for (int i = 0; i < 16; ++i) {
            int tloc = tg * 16 + i;
            z_tok[(size_t)(bh * 64 + tloc) * DIMS + c] = zs[c][tloc];
        }
    }
    // A fragments: 512 chunks (4 mtiles x 2 ksteps x 64 lanes), 2 per thread
    #pragma unroll
    for (int ii = 0; ii < 2; ++ii) {
        int ch  = tid + ii * 256;
        int mtl = ch >> 7;
        int st  = (ch >> 6) & 1;
        int l   = ch & 63;
        int tloc = mtl * 16 + (l & 15);
        int kb   = st * 32 + ((l >> 4) & 3) * 8;
        float rr = rn[tloc];
        v8s o;
        #pragma unroll
        for (int j = 0; j < 8; ++j) o[j] = bf16_rne(zs[kb + j][tloc] * rr);
        af[(size_t)((bh * 4 + mtl) * 2 + st) * 64 + l] = o;
    }
}

// ---------------------------------------------------------------------------
// GEMM config (pass1/pass2):
//  - 512 threads (8 waves), RT=4 m-tiles/wave -> block M = 512 tokens
//  - codes split 8-way: block streams 1024 codes = 64 tiles of 16
//  - chunks of 16 tiles (256 codes) staged in 32 KB LDS, 4 chunks
//  - grid = 64 M-blocks x 8 splits = 512 blocks = 2 blocks/CU
// ---------------------------------------------------------------------------
#define RT 4
#define CHUNK_TILES 16
#define TILES_PER_BLOCK 64
#define CHUNKS (TILES_PER_BLOCK / CHUNK_TILES)

__global__ __launch_bounds__(512, 4)
void pass1_kernel(const v8s* __restrict__ af, const v8s* __restrict__ ef,
                  unsigned* __restrict__ tokmax) {
    __shared__ v8s lds[CHUNK_TILES * 2 * 64];   // 32 KB
    const int tid  = threadIdx.x;
    const int lane = tid & 63;
    const int wave = tid >> 6;
    const int bm    = blockIdx.x >> 3;          // 0..63
    const int split = blockIdx.x & 7;
    const int tile0 = split * TILES_PER_BLOCK;

    const int mtb = bm * 32 + wave * RT;        // first m-tile of this wave
    v8s a[RT][2];
    #pragma unroll
    for (int r = 0; r < RT; ++r)
        #pragma unroll
        for (int s = 0; s < 2; ++s)
            a[r][s] = af[(size_t)((mtb + r) * 2 + s) * 64 + lane];

    v4f mx[RT];
    #pragma unroll
    for (int r = 0; r < RT; ++r) mx[r] = (v4f){-1e30f, -1e30f, -1e30f, -1e30f};

    const float4* gsrc = (const float4*)(ef + (size_t)tile0 * 2 * 64);
    float4* lf = (float4*)lds;
    float4 pre[4];
    #pragma unroll
    for (int i = 0; i < 4; ++i) pre[i] = gsrc[tid + i * 512];

    for (int c = 0; c < CHUNKS; ++c) {
        __syncthreads();
        #pragma unroll
        for (int i = 0; i < 4; ++i) lf[tid + i * 512] = pre[i];
        if (c + 1 < CHUNKS) {
            const float4* nx = gsrc + (size_t)(c + 1) * 2048;
            #pragma unroll
            for (int i = 0; i < 4; ++i) pre[i] = nx[tid + i * 512];
        }
        __syncthreads();
        #pragma unroll
        for (int j = 0; j < CHUNK_TILES; ++j) {
            v8s b0 = lds[(j * 2 + 0) * 64 + lane];
            v8s b1 = lds[(j * 2 + 1) * 64 + lane];
            #pragma unroll
            for (int r = 0; r < RT; ++r) {
                v4f t = (v4f){0.f, 0.f, 0.f, 0.f};
                t = __builtin_amdgcn_mfma_f32_16x16x32_bf16(a[r][0], b0, t, 0, 0, 0);
                t = __builtin_amdgcn_mfma_f32_16x16x32_bf16(a[r][1], b1, t, 0, 0, 0);
                mx[r][0] = fmaxf(mx[r][0], t[0]);
                mx[r][1] = fmaxf(mx[r][1], t[1]);
                mx[r][2] = fmaxf(mx[r][2], t[2]);
                mx[r][3] = fmaxf(mx[r][3], t[3]);
            }
        }
    }
    // reduce over the 16 code-columns (lanes sharing a 16-lane group)
    #pragma unroll
    for (int r = 0; r < RT; ++r)
        #pragma unroll
        for (int i = 0; i < 4; ++i) {
            float v = mx[r][i];
            v = fmaxf(v, __shfl_xor(v, 1, 64));
            v = fmaxf(v, __shfl_xor(v, 2, 64));
            v = fmaxf(v, __shfl_xor(v, 4, 64));
            v = fmaxf(v, __shfl_xor(v, 8, 64));
            mx[r][i] = v;
        }
    if ((lane & 15) == 0) {
        int q = lane >> 4;
        #pragma unroll
        for (int r = 0; r < RT; ++r)
            #pragma unroll
            for (int i = 0; i < 4; ++i) {
                int tok = (mtb + r) * 16 + q * 4 + i;
                atomicMax(&tokmax[tok], mono(mx[r][i]));
            }
    }
}

// ---------------------------------------------------------------------------
// Pass 2: same GEMM; codes with s_bf >= tokmax - MARGIN get exact fp32
// rescore (wave-cooperative dot) -> packed u64 atomicMax
// (max value, tie -> smallest code index).
// ---------------------------------------------------------------------------
__global__ __launch_bounds__(512, 4)
void pass2_kernel(const v8s* __restrict__ af, const v8s* __restrict__ ef,
                  const unsigned* __restrict__ tokmax,
                  const float* __restrict__ z_tok, const float* __restrict__ emb,
                  const float* __restrict__ invn,
                  unsigned long long* __restrict__ winner) {
    __shared__ v8s lds[CHUNK_TILES * 2 * 64];   // 32 KB
    const int tid  = threadIdx.x;
    const int lane = tid & 63;
    const int wave = tid >> 6;
    const int bm    = blockIdx.x >> 3;
    const int split = blockIdx.x & 7;
    const int tile0 = split * TILES_PER_BLOCK;

    const int mtb = bm * 32 + wave * RT;
    v8s a[RT][2];
    #pragma unroll
    for (int r = 0; r < RT; ++r)
        #pragma unroll
        for (int s = 0; s < 2; ++s)
            a[r][s] = af[(size_t)((mtb + r) * 2 + s) * 64 + lane];

    // per-lane thresholds for its 16 (row, reg) tokens
    float thr[RT][4];
    {
        int q = lane >> 4;
        #pragma unroll
        for (int r = 0; r < RT; ++r)
            #pragma unroll
            for (int i = 0; i < 4; ++i)
                thr[r][i] = demono(tokmax[(mtb + r) * 16 + q * 4 + i]) - MARGIN;
    }

    const float4* gsrc = (const float4*)(ef + (size_t)tile0 * 2 * 64);
    float4* lf = (float4*)lds;
    float4 pre[4];
    #pragma unroll
    for (int i = 0; i < 4; ++i) pre[i] = gsrc[tid + i * 512];

    for (int c = 0; c < CHUNKS; ++c) {
        __syncthreads();
        #pragma unroll
        for (int i = 0; i < 4; ++i) lf[tid + i * 512] = pre[i];
        if (c + 1 < CHUNKS) {
            const float4* nx = gsrc + (size_t)(c + 1) * 2048;
            #pragma unroll
            for (int i = 0; i < 4; ++i) pre[i] = nx[tid + i * 512];
        }
        __syncthreads();
        #pragma unroll 4
        for (int j = 0; j < CHUNK_TILES; ++j) {
            v8s b0 = lds[(j * 2 + 0) * 64 + lane];
            v8s b1 = lds[(j * 2 + 1) * 64 + lane];
            v4f acc[RT];
            #pragma unroll
            for (int r = 0; r < RT; ++r) {
                v4f t = (v4f){0.f, 0.f, 0.f, 0.f};
                t = __builtin_amdgcn_mfma_f32_16x16x32_bf16(a[r][0], b0, t, 0, 0, 0);
                t = __builtin_amdgcn_mfma_f32_16x16x32_bf16(a[r][1], b1, t, 0, 0, 0);
                acc[r] = t;
            }
            // per-lane candidate bitmask over the 16 (r,i) token slots
            unsigned pm = 0;
            #pragma unroll
            for (int r = 0; r < RT; ++r)
                #pragma unroll
                for (int i = 0; i < 4; ++i)
                    if (acc[r][i] >= thr[r][i]) pm |= (1u << (r * 4 + i));
            unsigned long long act = __ballot(pm != 0);
            if (act) {                               // wave-uniform, ~18% of j's
                const int ctile = tile0 + c * CHUNK_TILES + j;
                while (act) {
                    int sl = __ffsll(act) - 1;
                    act &= act - 1;
                    unsigned lm = __shfl(pm, sl, 64);   // that lane's mask (uniform)
                    const int code = ctile * 16 + (sl & 15);
                    while (lm) {
                        int bit = __ffs(lm) - 1;
                        lm &= lm - 1;
                        int r = bit >> 2, i = bit & 3;
                        int tok = (mtb + r) * 16 + ((sl >> 4) & 3) * 4 + i;
                        // exact fp32 rescore, whole wave cooperates
                        float p = z_tok[(size_t)tok * DIMS + lane] *
                                  emb[(size_t)code * DIMS + lane];
                        #pragma unroll
                        for (int o = 32; o; o >>= 1) p += __shfl_xor(p, o, 64);
                        float d = p * invn[code];
                        if (lane == 0) atomicMax(&winner[tok], pack_win(d, code));
                    }
                }
            }
        }
    }
}

// ---------------------------------------------------------------------------
// Finalize indices: unpack winner -> idx (int) + idxmap (float out)
// ---------------------------------------------------------------------------
__global__ void fin_idx_kernel(const unsigned long long* __restrict__ winner,
                               int* __restrict__ idx, float* __restrict__ idxmap) {
    int t = blockIdx.x * 256 + threadIdx.x;
    unsigned code = 0xFFFFFFFFu - (unsigned)(winner[t] & 0xFFFFFFFFull);
    idx[t] = (int)code;
    idxmap[t] = (float)code;
}

// ---------------------------------------------------------------------------
// K3: gather z_q, out = zv + (q - zv), SSE partial, histogram.
// ---------------------------------------------------------------------------
__global__ void gather_loss_kernel(const float* __restrict__ z,
                                   const float* __restrict__ emb,
                                   const int* __restrict__ idx,
                                   float* __restrict__ out,
                                   float* __restrict__ partial,
                                   int* __restrict__ hist) {
    __shared__ float red[256];
    const int tid  = threadIdx.x;
    const int lane = tid & 63;   // w
    const int wave = tid >> 6;
    const int bt   = blockIdx.x; // 0..511
    const int b    = bt >> 6;
    const int h    = bt & 63;

    const int t  = bt * 64 + lane;
    const int id = idx[t];
    const long base = (long)b * (C_ * H_ * W_) + h * W_ + lane;

    float sse = 0.f;
    #pragma unroll
    for (int cc = 0; cc < 16; ++cc) {
        const int c = wave * 16 + cc;
        const float q  = emb[id * DIMS + c];
        const float zv = z[base + (long)c * (H_ * W_)];
        out[base + (long)c * (H_ * W_)] = zv + (q - zv);  // exact ref expression
        const float d = q - zv;
        sse += d * d;
    }

    red[tid] = sse;
    __syncthreads();
    for (int s = 128; s > 0; s >>= 1) {
        if (tid < s) red[tid] += red[tid + s];
        __syncthreads();
    }
    if (tid == 0) partial[bt] = red[0];
    if (wave == 0) atomicAdd(&hist[id], 1);
}

// ---------------------------------------------------------------------------
// K4: finalize loss + perplexity. One block of 256 threads.
// ---------------------------------------------------------------------------
__global__ void finalize_kernel(const float* __restrict__ partial,
                                const int* __restrict__ hist,
                                float* __restrict__ out_scal) {
    __shared__ double red[256];
    const int tid = threadIdx.x;

    double s = 0.0;
    for (int i = tid; i < 512; i += 256) s += (double)partial[i];
    red[tid] = s;
    __syncthreads();
    for (int st = 128; st > 0; st >>= 1) {
        if (tid < st) red[tid] += red[tid + st];
        __syncthreads();
    }
    const double sse = red[0];
    __syncthreads();

    double e = 0.0;
    for (int k = tid; k < NUM_EMBED; k += 256) {
        float p = (float)hist[k] / (float)N_TOK;
        e += (double)(p * logf(p + 1e-10f));
    }
    red[tid] = e;
    __syncthreads();
    for (int st = 128; st > 0; st >>= 1) {
        if (tid < st) red[tid] += red[tid + st];
        __syncthreads();
    }
    if (tid == 0) {
        out_scal[0] = (float)(1.25 * sse / (double)N_ELEM);
        out_scal[1] = expf(-(float)red[0]);
    }
}

// ---------------------------------------------------------------------------
extern "C" void kernel_launch(void* const* d_in, const int* in_sizes, int n_in,
                              void* d_out, int out_size, void* d_ws, size_t ws_size,
                              hipStream_t stream) {
    const float* z   = (const float*)d_in[0];
    const float* emb = (const float*)d_in[1];
    float* o = (float*)d_out;

    // workspace layout (5.57 MB total; proven available in R2)
    char* ws = (char*)d_ws;
    v8s*  af      = (v8s*)ws;                                      // 4 MB
    v8s*  ef      = (v8s*)(ws + 4194304);                          // 1 MB
    unsigned long long* winner = (unsigned long long*)(ws + 5242880); // 256 KB
    unsigned* tokmax = (unsigned*)(ws + 5505024);                  // 128 KB
    int*   idx     = (int*)(ws + 5636096);                         // 128 KB
    float* invn    = (float*)(ws + 5767168);                       // 32 KB
    int*   hist    = (int*)(ws + 5799936);                         // 32 KB
    float* partial = (float*)(ws + 5832704);                       // 2 KB

    float* out_q      = o;                  // 2097152 floats
    float* out_scal   = o + N_ELEM;         // loss, perplexity
    float* out_idxmap = o + N_ELEM + 2;     // 32768 floats
    float* z_tok      = o;                  // reuse out_q region as fp32 token-major
                                            // scratch; overwritten by gather later

    hipMemsetAsync(tokmax, 0, N_TOK * sizeof(unsigned), stream);
    hipMemsetAsync(winner, 0, N_TOK * sizeof(unsigned long long), stream);
    hipMemsetAsync(hist,   0, NUM_EMBED * sizeof(int), stream);

    invnorm_kernel<<<NUM_EMBED / 4, 256, 0, stream>>>(emb, invn);
    en_frag_kernel<<<256, 256, 0, stream>>>(emb, invn, ef);
    z_prep_kernel<<<512, 256, 0, stream>>>(z, z_tok, af);
    pass1_kernel<<<512, 512, 0, stream>>>(af, ef, tokmax);
    pass2_kernel<<<512, 512, 0, stream>>>(af, ef, tokmax, z_tok, emb, invn, winner);
    fin_idx_kernel<<<N_TOK / 256, 256, 0, stream>>>(winner, idx, out_idxmap);
    gather_loss_kernel<<<N_TOK / 64, 256, 0, stream>>>(z, emb, idx, out_q, partial, hist);
    finalize_kernel<<<1, 256, 0, stream>>>(partial, hist, out_scal);
}